// Round 3
// baseline (174.198 us; speedup 1.0000x reference)
//
#include <hip/hip_runtime.h>
#include <hip/hip_bf16.h>
#include <stdint.h>

#define CH   384
#define HID  512
#define NHD  8
#define MTOT 32768   // B*H*W tokens

typedef __attribute__((ext_vector_type(8))) short bf16x8;
typedef __attribute__((ext_vector_type(4))) float f32x4;
typedef unsigned short u16;

__device__ __forceinline__ float bf2f(u16 v){ return __uint_as_float(((unsigned)v)<<16); }
__device__ __forceinline__ u16 f2bf(float f){
  unsigned u = __float_as_uint(f);
  return (u16)((u + 0x7fffu + ((u>>16)&1u)) >> 16);
}
__device__ __forceinline__ void gload_lds16(const void* g, void* l){
  __builtin_amdgcn_global_load_lds((const __attribute__((address_space(1))) void*)g,
                                   (__attribute__((address_space(3))) void*)l, 16, 0, 0);
}

// ---------------- fp32 -> bf16 convert ----------------
__global__ void k_cvt(const float* __restrict__ in, u16* __restrict__ out, int n4){
  int i = blockIdx.x*blockDim.x + threadIdx.x;
  int stride = gridDim.x*blockDim.x;
  for (; i < n4; i += stride){
    float4 v = ((const float4*)in)[i];
    ushort4 o; o.x=f2bf(v.x); o.y=f2bf(v.y); o.z=f2bf(v.z); o.w=f2bf(v.w);
    ((ushort4*)out)[i] = o;
  }
}

// ---------------- GEMM1 v2: proj = x@W1^T + b1, fused split + x*tanh(s) ----------------
// BM=128, BN=192 (64 h-cols x 3 segs, laid out [hblk4][seg3][16]), BK=32.
// 256 thr, 4 waves 2Mx2N -> wave tile 64 rows x 96 B-rows (32 h-cols, all 3 segs).
// Double-buffered LDS (40KB), 2-phase pipeline. Coalesced epilogue via LDS transpose.
__global__ __launch_bounds__(256)
void k_gemm1(const u16* __restrict__ xb, const u16* __restrict__ w1b,
             const float* __restrict__ b1,
             u16* __restrict__ xh, u16* __restrict__ yb)
{
  __shared__ short lds[20480];  // A0[0,4096) A1[4096,8192) B0[8192,14336) B1[14336,20480)
  const int tid = threadIdx.x;
  const int w = tid >> 6, lw = tid & 63;
  const int wm = w >> 1, wn = w & 1;
  const int m0 = blockIdx.x * 128;
  const int h0 = blockIdx.y * 64;
  const int lc = lw & 15, lk = lw >> 4;

  f32x4 acc[4][6] = {};   // [mi][hb2*3+seg]

  // ---- staging descriptors: 20 chunks (8 A + 12 B), wave w -> chunks w*5..w*5+4
  // chunk = 16 rows x 32 cols bf16 (1KB). LDS[r][i] = G[r][i ^ (r&3)] (16B slices).
  const u16* gsrc[5]; int ldst[5]; int lstr[5];
  {
    const int sl = ((lw & 3) ^ ((lw >> 2) & 3)) * 8;   // r&3 == (lw>>2)&3 for all chunks
    #pragma unroll
    for (int i = 0; i < 5; ++i){
      int c = w*5 + i;
      if (c < 8){
        int r = c*16 + (lw >> 2);
        gsrc[i] = xb + (size_t)(m0 + r)*CH + sl;
        ldst[i] = c*512; lstr[i] = 4096;
      } else {
        int cb = c - 8;
        int grow = (cb % 3)*HID + h0 + (cb/3)*16 + (lw >> 2);
        gsrc[i] = w1b + (size_t)grow*CH + sl;
        ldst[i] = 8192 + cb*512; lstr[i] = 6144;
      }
    }
  }
  auto STAGE = [&](int buf, int kt){
    #pragma unroll
    for (int i = 0; i < 5; ++i)
      gload_lds16(gsrc[i] + kt*32, &lds[ldst[i] + buf*lstr[i]]);
  };

  const int sA = (lk ^ (lc & 3)) * 8;   // swizzled k-slice (bases are mult. of 16 rows)
  auto COMPUTE = [&](const short* pa, const short* pb){
    bf16x8 af[4], bv[6];
    #pragma unroll
    for (int mi = 0; mi < 4; ++mi)
      af[mi] = *(const bf16x8*)&pa[(wm*64 + mi*16 + lc)*32 + sA];
    #pragma unroll
    for (int nj = 0; nj < 6; ++nj)
      bv[nj] = *(const bf16x8*)&pb[(wn*96 + (nj/3)*48 + (nj%3)*16 + lc)*32 + sA];
    #pragma unroll
    for (int mi = 0; mi < 4; ++mi)
      #pragma unroll
      for (int nj = 0; nj < 6; ++nj)
        acc[mi][nj] = __builtin_amdgcn_mfma_f32_16x16x32_bf16(af[mi], bv[nj], acc[mi][nj], 0,0,0);
  };

  // ---- 2-phase double-buffered K-loop: 12 steps of BK=32 ----
  STAGE(0, 0);
  __syncthreads();
  #pragma unroll 1
  for (int kt2 = 0; kt2 < 6; ++kt2){
    STAGE(1, 2*kt2 + 1);
    COMPUTE(lds + 0, lds + 8192);
    __syncthreads();
    if (kt2 < 5) STAGE(0, 2*kt2 + 2);
    COMPUTE(lds + 4096, lds + 14336);
    __syncthreads();
  }

  // ---- epilogue: combine + coalesced store via LDS transpose ----
  __syncthreads();   // all waves done reading A1/B1 before reuse
  {
    short* ep  = &lds[w*2560];           // 64 rows x 40 pitch (80B, 16B-aligned)
    short* ep2 = &lds[10240 + w*2560];
    const int gr = m0 + wm*64 + lw;
    const int gc = h0 + wn*32;
    float bs[2], bx[2], by[2];
    #pragma unroll
    for (int hb = 0; hb < 2; ++hb){
      int col = gc + hb*16 + lc;
      bs[hb] = b1[col]; bx[hb] = b1[512 + col]; by[hb] = b1[1024 + col];
    }
    #pragma unroll
    for (int mi = 0; mi < 4; ++mi)
      #pragma unroll
      for (int hb = 0; hb < 2; ++hb)
        #pragma unroll
        for (int j = 0; j < 4; ++j){
          float sv = acc[mi][hb*3 + 0][j] + bs[hb];
          float xv = (acc[mi][hb*3 + 1][j] + bx[hb]) * tanhf(sv);
          float yv = acc[mi][hb*3 + 2][j] + by[hb];
          int row = mi*16 + lk*4 + j;
          ep [row*40 + hb*16 + lc] = (short)f2bf(xv);
          ep2[row*40 + hb*16 + lc] = (short)f2bf(yv);
        }
    #pragma unroll
    for (int q = 0; q < 4; ++q){
      bf16x8 v = *(const bf16x8*)&ep[lw*40 + q*8];
      *(bf16x8*)&xh[(size_t)gr*HID + gc + q*8] = v;
    }
    #pragma unroll
    for (int q = 0; q < 4; ++q){
      bf16x8 v = *(const bf16x8*)&ep2[lw*40 + q*8];
      *(bf16x8*)&yb[(size_t)gr*HID + gc + q*8] = v;
    }
  }
}

// ---------------- Attention: one wave per (head, batch, block) ----------------
__global__ __launch_bounds__(64, 3)
void k_attn(const float* __restrict__ aw, const float* __restrict__ wts,
            const int* __restrict__ idxs,
            const u16* __restrict__ xh, const u16* __restrict__ yb,
            u16* __restrict__ zb)
{
  __shared__ short lKv[64*96];   // kv^T [d][t], XOR-swizzled, 12 KB
  const int tid = threadIdx.x;   // one wave
  const int bid = blockIdx.x;    // ((h*8+b)*64+n)
  const int h = bid >> 9;
  const int b = (bid >> 6) & 7;
  const int n = bid & 63;
  const int bh = n >> 3, bw = n & 7;

  // ---- stage kv^T: 48 token-pairs x 8 dim-groups, pure bf16 copy ----
  {
    const int dg = tid & 7;
    const int pr = tid >> 3;
    #pragma unroll
    for (int it = 0; it < 6; ++it){
      int pair = it*8 + pr;
      int t0 = pair*2;
      size_t r0, r1;
      if (t0 < 64){
        int pix = (bh*8 + (t0>>3))*64 + bw*8 + (t0&7);
        r0 = (size_t)b*4096 + pix;
        r1 = r0 + 1;
      } else {
        int e = (b*64+n)*32 + (t0-64);
        r0 = (size_t)b*4096 + idxs[e];
        r1 = (size_t)b*4096 + idxs[e+1];
      }
      bf16x8 v0 = *(const bf16x8*)&xh[r0*HID + h*64 + dg*8];
      bf16x8 v1 = *(const bf16x8*)&xh[r1*HID + h*64 + dg*8];
      #pragma unroll
      for (int j = 0; j < 8; ++j){
        int d = dg*8 + j;
        int elem = (d*96 + t0) ^ (dg<<3);
        unsigned pk = (unsigned)(u16)v0[j] | ((unsigned)(u16)v1[j] << 16);
        *(unsigned*)&lKv[elem] = pk;
      }
    }
  }

  // ---- A-fragments direct from global fp32, w folded into k-step 2 ----
  float wv[8];
  {
    const float* wp = wts + (size_t)(b*64+n)*32 + (tid>>4)*8;
    float4 a = *(const float4*)wp, c = *(const float4*)(wp+4);
    wv[0]=a.x; wv[1]=a.y; wv[2]=a.z; wv[3]=a.w;
    wv[4]=c.x; wv[5]=c.y; wv[6]=c.z; wv[7]=c.w;
  }
  const float* awp = aw + (size_t)bid * (64*96);
  bf16x8 af[3][4];
  #pragma unroll
  for (int ks = 0; ks < 3; ++ks){
    #pragma unroll
    for (int mi = 0; mi < 4; ++mi){
      const float* p = awp + (size_t)(mi*16 + (tid&15))*96 + ks*32 + (tid>>4)*8;
      float4 f0 = *(const float4*)p;
      float4 f1 = *(const float4*)(p+4);
      float t[8] = {f0.x,f0.y,f0.z,f0.w,f1.x,f1.y,f1.z,f1.w};
      #pragma unroll
      for (int j = 0; j < 8; ++j){
        float v = (ks == 2) ? t[j]*wv[j] : t[j];
        af[ks][mi][j] = (short)f2bf(v);
      }
    }
  }
  __syncthreads();

  // ---- MFMA: 64x96 @ 96x64 ----
  f32x4 acc[4][4] = {};
  const int lc = tid & 15, lk = tid >> 4;
  #pragma unroll
  for (int ks = 0; ks < 3; ++ks){
    bf16x8 bv[4];
    #pragma unroll
    for (int nj = 0; nj < 4; ++nj){
      int d = nj*16 + lc;
      int idx = (d*96 + ks*32 + lk*8) ^ ((d>>3)<<3);
      bv[nj] = *(const bf16x8*)&lKv[idx];
    }
    #pragma unroll
    for (int mi = 0; mi < 4; ++mi)
      #pragma unroll
      for (int nj = 0; nj < 4; ++nj)
        acc[mi][nj] = __builtin_amdgcn_mfma_f32_16x16x32_bf16(af[ks][mi], bv[nj], acc[mi][nj], 0,0,0);
  }

  // ---- epilogue: z = out * y (bf16) ----
  #pragma unroll
  for (int mi = 0; mi < 4; ++mi){
    #pragma unroll
    for (int nj = 0; nj < 4; ++nj){
      int d = nj*16 + lc;
      size_t gcol = (size_t)h*64 + d;
      #pragma unroll
      for (int j = 0; j < 4; ++j){
        int q = mi*16 + lk*4 + j;
        int pix = (bh*8 + (q>>3))*64 + bw*8 + (q&7);
        size_t r = (size_t)b*4096 + pix;
        float yv = bf2f(yb[r*HID + gcol]);
        zb[r*HID + gcol] = f2bf(acc[mi][nj][j] * yv);
      }
    }
  }
}

// ---------------- GEMM2: out = z@W2^T + b2 (fp32 out) ----------------
__global__ void k_gemm2(const u16* __restrict__ zb, const u16* __restrict__ w2b,
                        const float* __restrict__ b2, float* __restrict__ out)
{
  __shared__ short lA[128*64];
  __shared__ short lB[128*64];
  const int tid = threadIdx.x;
  const int w = tid>>6, lw = tid&63;
  const int wm = w>>1, wn = w&1;
  const int m0 = blockIdx.x*128, n0 = blockIdx.y*128;

  f32x4 acc[4][4] = {};

  for (int kt=0; kt<HID/64; ++kt){
    int kbase = kt*64;
    #pragma unroll
    for (int i=0; i<4; ++i){
      int chunk = i*4 + w;
      int row = chunk*8 + (lw>>3);
      int sl = (lw&7) ^ (row&7);
      gload_lds16(zb  + (size_t)(m0+row)*HID + kbase + sl*8, &lA[chunk*512]);
      gload_lds16(w2b + (size_t)(n0+row)*HID + kbase + sl*8, &lB[chunk*512]);
    }
    __syncthreads();
    #pragma unroll
    for (int ks=0; ks<2; ++ks){
      bf16x8 af[4], bb[4];
      #pragma unroll
      for (int mi=0; mi<4; ++mi){
        int row = wm*64 + mi*16 + (lw&15);
        int sl = (ks*4 + (lw>>4)) ^ (row&7);
        af[mi] = *(const bf16x8*)&lA[row*64 + sl*8];
      }
      #pragma unroll
      for (int nj=0; nj<4; ++nj){
        int row = wn*64 + nj*16 + (lw&15);
        int sl = (ks*4 + (lw>>4)) ^ (row&7);
        bb[nj] = *(const bf16x8*)&lB[row*64 + sl*8];
      }
      #pragma unroll
      for (int mi=0; mi<4; ++mi)
        #pragma unroll
        for (int nj=0; nj<4; ++nj)
          acc[mi][nj] = __builtin_amdgcn_mfma_f32_16x16x32_bf16(af[mi], bb[nj], acc[mi][nj], 0,0,0);
    }
    __syncthreads();
  }

  const int lc = lw&15, lr4 = (lw>>4)*4;
  #pragma unroll
  for (int nj=0; nj<4; ++nj){
    int col = n0 + wn*64 + nj*16 + lc;
    float bias = b2[col];
    #pragma unroll
    for (int mi=0; mi<4; ++mi){
      #pragma unroll
      for (int j=0; j<4; ++j){
        int row = m0 + wm*64 + mi*16 + lr4 + j;
        out[(size_t)row*CH + col] = acc[mi][nj][j] + bias;
      }
    }
  }
}

extern "C" void kernel_launch(void* const* d_in, const int* in_sizes, int n_in,
                              void* d_out, int out_size, void* d_ws, size_t ws_size,
                              hipStream_t stream) {
  const float* x   = (const float*)d_in[0];
  const float* aw  = (const float*)d_in[1];
  const float* wts = (const float*)d_in[2];
  const float* w1  = (const float*)d_in[3];
  const float* b1  = (const float*)d_in[4];
  const float* w2  = (const float*)d_in[5];
  const float* b2  = (const float*)d_in[6];
  const int*   idx = (const int*)d_in[7];
  float* out = (float*)d_out;

  char* ws = (char*)d_ws;
  u16* x_bf  = (u16*)(ws);                              // 32768*384*2  = 25165824
  u16* w1_bf = (u16*)(ws + 25165824);                   // 1536*384*2   = 1179648
  u16* w2_bf = (u16*)(ws + 26345472);                   // 384*512*2    = 393216
  u16* xh_bf = (u16*)(ws + 26738688);                   // 32768*512*2  = 33554432
  u16* y_bf  = (u16*)(ws + 60293120);                   // 33554432
  u16* z_bf  = (u16*)(ws + 93847552);                   // 33554432

  k_cvt<<<2048, 256, 0, stream>>>(x,  x_bf,  MTOT*CH/4);
  k_cvt<<<576,  256, 0, stream>>>(w1, w1_bf, 3*HID*CH/4);
  k_cvt<<<192,  256, 0, stream>>>(w2, w2_bf, CH*HID/4);

  k_gemm1<<<dim3(MTOT/128, HID/64), 256, 0, stream>>>(x_bf, w1_bf, b1, xh_bf, y_bf);
  k_attn<<<NHD*8*64, 64, 0, stream>>>(aw, wts, idx, xh_bf, y_bf, z_bf);
  k_gemm2<<<dim3(MTOT/128, CH/128), 256, 0, stream>>>(z_bf, w2_bf, b2, out);
}

// Round 4
// 170.992 us; speedup vs baseline: 1.0188x; 1.0188x over previous
//
#include <hip/hip_runtime.h>
#include <hip/hip_bf16.h>
#include <stdint.h>

#define CH   384
#define HID  512
#define NHD  8
#define MTOT 32768   // B*H*W tokens

typedef __attribute__((ext_vector_type(8))) short bf16x8;
typedef __attribute__((ext_vector_type(4))) float f32x4;
typedef unsigned short u16;

__device__ __forceinline__ float bf2f(u16 v){ return __uint_as_float(((unsigned)v)<<16); }
__device__ __forceinline__ u16 f2bf(float f){
  unsigned u = __float_as_uint(f);
  return (u16)((u + 0x7fffu + ((u>>16)&1u)) >> 16);
}
__device__ __forceinline__ void gload_lds16(const void* g, void* l){
  __builtin_amdgcn_global_load_lds((const __attribute__((address_space(1))) void*)g,
                                   (__attribute__((address_space(3))) void*)l, 16, 0, 0);
}

// ---------------- fp32 -> bf16 convert ----------------
__global__ void k_cvt(const float* __restrict__ in, u16* __restrict__ out, int n4){
  int i = blockIdx.x*blockDim.x + threadIdx.x;
  int stride = gridDim.x*blockDim.x;
  for (; i < n4; i += stride){
    float4 v = ((const float4*)in)[i];
    ushort4 o; o.x=f2bf(v.x); o.y=f2bf(v.y); o.z=f2bf(v.z); o.w=f2bf(v.w);
    ((ushort4*)out)[i] = o;
  }
}

// ---------------- GEMM1 v3: proj = x@W1^T + b1, fused split + x*tanh(s) ----------------
// BM=128, BN=192 (64 h-cols x 3 segs, [hblk4][seg3][16]), BK=64 (proven conflict-free
// (l&7)^(l>>3) swizzle). Single 40KB LDS buffer -> 4 blocks/CU implicit overlap.
// 4 waves 2Mx2N, wave tile 64x96 (24 MFMA : 10 ds_read per ks). Coalesced epilogue.
__global__ __launch_bounds__(256)
void k_gemm1(const u16* __restrict__ xb, const u16* __restrict__ w1b,
             const float* __restrict__ b1,
             u16* __restrict__ xh, u16* __restrict__ yb)
{
  __shared__ short lds[20480];  // A [0,8192)  B [8192,20480)
  const int tid = threadIdx.x;
  const int w = tid >> 6, lw = tid & 63;
  const int wm = w >> 1, wn = w & 1;
  const int m0 = blockIdx.x * 128;
  const int h0 = blockIdx.y * 64;
  const int lc = lw & 15, lk = lw >> 4;

  f32x4 acc[4][6] = {};   // [mi][hb*3+seg]

  // ---- staging: 40 chunks (16 A + 24 B), 8 rows x 128B each; wave w -> 10 chunks.
  // LDS[row][s] = G[row][s ^ (row&7)] in 16B slices; lane slice = (l&7)^(l>>3).
  const int sl = (lw & 7) ^ (lw >> 3);
  const int rsub = lw >> 3;
  const u16* gsrc[10]; int ldst[10];
  #pragma unroll
  for (int i = 0; i < 10; ++i){
    int c = w*10 + i;
    if (c < 16){
      int r = c*8 + rsub;
      gsrc[i] = xb + (size_t)(m0 + r)*CH + sl*8;
      ldst[i] = c*512;
    } else {
      int cb = c - 16;
      int rb = cb*8 + rsub;
      int hb = rb/48, rem = rb - hb*48;
      int seg = rem >> 4, ii = rem & 15;
      gsrc[i] = w1b + (size_t)(seg*HID + h0 + hb*16 + ii)*CH + sl*8;
      ldst[i] = 8192 + cb*512;
    }
  }

  // ---- K-loop: 6 steps of BK=64, single buffer, m97-style ----
  #pragma unroll 1
  for (int kt = 0; kt < 6; ++kt){
    #pragma unroll
    for (int i = 0; i < 10; ++i)
      gload_lds16(gsrc[i] + kt*64, &lds[ldst[i]]);
    __syncthreads();
    #pragma unroll
    for (int ks = 0; ks < 2; ++ks){
      bf16x8 af[4], bv[6];
      #pragma unroll
      for (int mi = 0; mi < 4; ++mi){
        int row = wm*64 + mi*16 + lc;
        int s = (ks*4 + lk) ^ (lc & 7);
        af[mi] = *(const bf16x8*)&lds[row*64 + s*8];
      }
      #pragma unroll
      for (int nj = 0; nj < 6; ++nj){
        int row = wn*96 + (nj/3)*48 + (nj%3)*16 + lc;
        int s = (ks*4 + lk) ^ (lc & 7);
        bv[nj] = *(const bf16x8*)&lds[8192 + row*64 + s*8];
      }
      #pragma unroll
      for (int mi = 0; mi < 4; ++mi)
        #pragma unroll
        for (int nj = 0; nj < 6; ++nj)
          acc[mi][nj] = __builtin_amdgcn_mfma_f32_16x16x32_bf16(af[mi], bv[nj], acc[mi][nj], 0,0,0);
    }
    __syncthreads();
  }

  // ---- epilogue: combine + coalesced store via LDS transpose ----
  {
    short* ep  = &lds[w*2560];            // 64 rows x 40-short pitch
    short* ep2 = &lds[10240 + w*2560];
    const int gr = m0 + wm*64 + lw;
    const int gc = h0 + wn*32;
    float bs[2], bx[2], by[2];
    #pragma unroll
    for (int hb = 0; hb < 2; ++hb){
      int col = gc + hb*16 + lc;
      bs[hb] = b1[col]; bx[hb] = b1[512 + col]; by[hb] = b1[1024 + col];
    }
    #pragma unroll
    for (int mi = 0; mi < 4; ++mi)
      #pragma unroll
      for (int hb = 0; hb < 2; ++hb)
        #pragma unroll
        for (int j = 0; j < 4; ++j){
          float sv = acc[mi][hb*3 + 0][j] + bs[hb];
          float xv = (acc[mi][hb*3 + 1][j] + bx[hb]) * tanhf(sv);
          float yv = acc[mi][hb*3 + 2][j] + by[hb];
          int row = mi*16 + lk*4 + j;
          ep [row*40 + hb*16 + lc] = (short)f2bf(xv);
          ep2[row*40 + hb*16 + lc] = (short)f2bf(yv);
        }
    __syncthreads();
    #pragma unroll
    for (int q = 0; q < 4; ++q){
      bf16x8 v = *(const bf16x8*)&ep[lw*40 + q*8];
      *(bf16x8*)&xh[(size_t)gr*HID + gc + q*8] = v;
    }
    #pragma unroll
    for (int q = 0; q < 4; ++q){
      bf16x8 v = *(const bf16x8*)&ep2[lw*40 + q*8];
      *(bf16x8*)&yb[(size_t)gr*HID + gc + q*8] = v;
    }
  }
}

// ---------------- Attention: one wave per (head, batch, block) ----------------
__global__ __launch_bounds__(64, 3)
void k_attn(const float* __restrict__ aw, const float* __restrict__ wts,
            const int* __restrict__ idxs,
            const u16* __restrict__ xh, const u16* __restrict__ yb,
            u16* __restrict__ zb)
{
  __shared__ short lKv[64*96];   // kv^T [d][t], XOR-swizzled, 12 KB
  const int tid = threadIdx.x;   // one wave
  const int bid = blockIdx.x;    // ((h*8+b)*64+n)
  const int h = bid >> 9;
  const int b = (bid >> 6) & 7;
  const int n = bid & 63;
  const int bh = n >> 3, bw = n & 7;

  // ---- stage kv^T: 48 token-pairs x 8 dim-groups, pure bf16 copy ----
  {
    const int dg = tid & 7;
    const int pr = tid >> 3;
    #pragma unroll
    for (int it = 0; it < 6; ++it){
      int pair = it*8 + pr;
      int t0 = pair*2;
      size_t r0, r1;
      if (t0 < 64){
        int pix = (bh*8 + (t0>>3))*64 + bw*8 + (t0&7);
        r0 = (size_t)b*4096 + pix;
        r1 = r0 + 1;
      } else {
        int e = (b*64+n)*32 + (t0-64);
        r0 = (size_t)b*4096 + idxs[e];
        r1 = (size_t)b*4096 + idxs[e+1];
      }
      bf16x8 v0 = *(const bf16x8*)&xh[r0*HID + h*64 + dg*8];
      bf16x8 v1 = *(const bf16x8*)&xh[r1*HID + h*64 + dg*8];
      #pragma unroll
      for (int j = 0; j < 8; ++j){
        int d = dg*8 + j;
        int elem = (d*96 + t0) ^ (dg<<3);
        unsigned pk = (unsigned)(u16)v0[j] | ((unsigned)(u16)v1[j] << 16);
        *(unsigned*)&lKv[elem] = pk;
      }
    }
  }

  // ---- A-fragments direct from global fp32, w folded into k-step 2 ----
  float wv[8];
  {
    const float* wp = wts + (size_t)(b*64+n)*32 + (tid>>4)*8;
    float4 a = *(const float4*)wp, c = *(const float4*)(wp+4);
    wv[0]=a.x; wv[1]=a.y; wv[2]=a.z; wv[3]=a.w;
    wv[4]=c.x; wv[5]=c.y; wv[6]=c.z; wv[7]=c.w;
  }
  const float* awp = aw + (size_t)bid * (64*96);
  bf16x8 af[3][4];
  #pragma unroll
  for (int ks = 0; ks < 3; ++ks){
    #pragma unroll
    for (int mi = 0; mi < 4; ++mi){
      const float* p = awp + (size_t)(mi*16 + (tid&15))*96 + ks*32 + (tid>>4)*8;
      float4 f0 = *(const float4*)p;
      float4 f1 = *(const float4*)(p+4);
      float t[8] = {f0.x,f0.y,f0.z,f0.w,f1.x,f1.y,f1.z,f1.w};
      #pragma unroll
      for (int j = 0; j < 8; ++j){
        float v = (ks == 2) ? t[j]*wv[j] : t[j];
        af[ks][mi][j] = (short)f2bf(v);
      }
    }
  }
  __syncthreads();

  // ---- MFMA: 64x96 @ 96x64 ----
  f32x4 acc[4][4] = {};
  const int lc = tid & 15, lk = tid >> 4;
  #pragma unroll
  for (int ks = 0; ks < 3; ++ks){
    bf16x8 bv[4];
    #pragma unroll
    for (int nj = 0; nj < 4; ++nj){
      int d = nj*16 + lc;
      int idx = (d*96 + ks*32 + lk*8) ^ ((d>>3)<<3);
      bv[nj] = *(const bf16x8*)&lKv[idx];
    }
    #pragma unroll
    for (int mi = 0; mi < 4; ++mi)
      #pragma unroll
      for (int nj = 0; nj < 4; ++nj)
        acc[mi][nj] = __builtin_amdgcn_mfma_f32_16x16x32_bf16(af[ks][mi], bv[nj], acc[mi][nj], 0,0,0);
  }

  // ---- epilogue: z = out * y (bf16) ----
  #pragma unroll
  for (int mi = 0; mi < 4; ++mi){
    #pragma unroll
    for (int nj = 0; nj < 4; ++nj){
      int d = nj*16 + lc;
      size_t gcol = (size_t)h*64 + d;
      #pragma unroll
      for (int j = 0; j < 4; ++j){
        int q = mi*16 + lk*4 + j;
        int pix = (bh*8 + (q>>3))*64 + bw*8 + (q&7);
        size_t r = (size_t)b*4096 + pix;
        float yv = bf2f(yb[r*HID + gcol]);
        zb[r*HID + gcol] = f2bf(acc[mi][nj][j] * yv);
      }
    }
  }
}

// ---------------- GEMM2: out = z@W2^T + b2 (fp32 out) ----------------
__global__ void k_gemm2(const u16* __restrict__ zb, const u16* __restrict__ w2b,
                        const float* __restrict__ b2, float* __restrict__ out)
{
  __shared__ short lA[128*64];
  __shared__ short lB[128*64];
  const int tid = threadIdx.x;
  const int w = tid>>6, lw = tid&63;
  const int wm = w>>1, wn = w&1;
  const int m0 = blockIdx.x*128, n0 = blockIdx.y*128;

  f32x4 acc[4][4] = {};

  for (int kt=0; kt<HID/64; ++kt){
    int kbase = kt*64;
    #pragma unroll
    for (int i=0; i<4; ++i){
      int chunk = i*4 + w;
      int row = chunk*8 + (lw>>3);
      int sl2 = (lw&7) ^ (row&7);
      gload_lds16(zb  + (size_t)(m0+row)*HID + kbase + sl2*8, &lA[chunk*512]);
      gload_lds16(w2b + (size_t)(n0+row)*HID + kbase + sl2*8, &lB[chunk*512]);
    }
    __syncthreads();
    #pragma unroll
    for (int ks=0; ks<2; ++ks){
      bf16x8 af[4], bb[4];
      #pragma unroll
      for (int mi=0; mi<4; ++mi){
        int row = wm*64 + mi*16 + (lw&15);
        int s = (ks*4 + (lw>>4)) ^ (row&7);
        af[mi] = *(const bf16x8*)&lA[row*64 + s*8];
      }
      #pragma unroll
      for (int nj=0; nj<4; ++nj){
        int row = wn*64 + nj*16 + (lw&15);
        int s = (ks*4 + (lw>>4)) ^ (row&7);
        bb[nj] = *(const bf16x8*)&lB[row*64 + s*8];
      }
      #pragma unroll
      for (int mi=0; mi<4; ++mi)
        #pragma unroll
        for (int nj=0; nj<4; ++nj)
          acc[mi][nj] = __builtin_amdgcn_mfma_f32_16x16x32_bf16(af[mi], bb[nj], acc[mi][nj], 0,0,0);
    }
    __syncthreads();
  }

  const int lc = lw&15, lr4 = (lw>>4)*4;
  #pragma unroll
  for (int nj=0; nj<4; ++nj){
    int col = n0 + wn*64 + nj*16 + lc;
    float bias = b2[col];
    #pragma unroll
    for (int mi=0; mi<4; ++mi){
      #pragma unroll
      for (int j=0; j<4; ++j){
        int row = m0 + wm*64 + mi*16 + lr4 + j;
        out[(size_t)row*CH + col] = acc[mi][nj][j] + bias;
      }
    }
  }
}

extern "C" void kernel_launch(void* const* d_in, const int* in_sizes, int n_in,
                              void* d_out, int out_size, void* d_ws, size_t ws_size,
                              hipStream_t stream) {
  const float* x   = (const float*)d_in[0];
  const float* aw  = (const float*)d_in[1];
  const float* wts = (const float*)d_in[2];
  const float* w1  = (const float*)d_in[3];
  const float* b1  = (const float*)d_in[4];
  const float* w2  = (const float*)d_in[5];
  const float* b2  = (const float*)d_in[6];
  const int*   idx = (const int*)d_in[7];
  float* out = (float*)d_out;

  char* ws = (char*)d_ws;
  u16* x_bf  = (u16*)(ws);                              // 32768*384*2  = 25165824
  u16* w1_bf = (u16*)(ws + 25165824);                   // 1536*384*2   = 1179648
  u16* w2_bf = (u16*)(ws + 26345472);                   // 384*512*2    = 393216
  u16* xh_bf = (u16*)(ws + 26738688);                   // 32768*512*2  = 33554432
  u16* y_bf  = (u16*)(ws + 60293120);                   // 33554432
  u16* z_bf  = (u16*)(ws + 93847552);                   // 33554432

  k_cvt<<<2048, 256, 0, stream>>>(x,  x_bf,  MTOT*CH/4);
  k_cvt<<<576,  256, 0, stream>>>(w1, w1_bf, 3*HID*CH/4);
  k_cvt<<<192,  256, 0, stream>>>(w2, w2_bf, CH*HID/4);

  k_gemm1<<<dim3(MTOT/128, HID/64), 256, 0, stream>>>(x_bf, w1_bf, b1, xh_bf, y_bf);
  k_attn<<<NHD*8*64, 64, 0, stream>>>(aw, wts, idx, xh_bf, y_bf, z_bf);
  k_gemm2<<<dim3(MTOT/128, CH/128), 256, 0, stream>>>(z_bf, w2_bf, b2, out);
}